// Round 6
// baseline (1268.140 us; speedup 1.0000x reference)
//
#include <hip/hip_runtime.h>
#include <cstdint>
#include <cmath>

#define HW48 2304   // 48*48 positions
#define F9   2304   // 256*9 features

typedef _Float16 half8_t __attribute__((ext_vector_type(8)));
typedef float floatx4 __attribute__((ext_vector_type(4)));

// ---------------- pos-encode: dst = src + conv3x3(posgrid) ----------------
__global__ void enc_kernel(const float* __restrict__ src, const float* __restrict__ w,
                           const float* __restrict__ b, float* __restrict__ dst,
                           int C, int H, int ms, int total) {
  int idx = blockIdx.x * blockDim.x + threadIdx.x;
  if (idx >= total) return;
  int x = idx % H;
  int y = (idx / H) % H;
  int c = (idx / (H * H)) % C;
  float scale = (float)((double)ms / (double)H);
  float msm1 = (float)(ms - 1);
  float conv = b[c];
#pragma unroll
  for (int dy = 0; dy < 3; ++dy) {
    int yy = y + dy - 1;
    if (yy < 0 || yy >= H) continue;
    float sy = fminf(fmaxf((yy + 0.5f) * scale - 0.5f, 0.0f), msm1);
    float g0 = -1.0f + 2.0f * sy / msm1;
#pragma unroll
    for (int dx = 0; dx < 3; ++dx) {
      int xx = x + dx - 1;
      if (xx < 0 || xx >= H) continue;
      float sx = fminf(fmaxf((xx + 0.5f) * scale - 0.5f, 0.0f), msm1);
      float g1 = -1.0f + 2.0f * sx / msm1;
      conv += w[((c * 2 + 0) * 3 + dy) * 3 + dx] * g0
            + w[((c * 2 + 1) * 3 + dy) * 3 + dx] * g1;
    }
  }
  dst[idx] = src[idx] + conv;
}

// ---------------- unfold(3,1,1) + l2-norm -> split-fp16 (hi, lo) ----------
__global__ void unfold_norm_kernel(const float* __restrict__ src,
                                   _Float16* __restrict__ dhi,
                                   _Float16* __restrict__ dlo) {
  int pos = blockIdx.x;          // 0..2303
  int n = blockIdx.y;
  int y = pos / 48, x = pos - (pos / 48) * 48;
  int tid = threadIdx.x;         // 256
  const float* s = src + (size_t)n * 256 * HW48;
  float v[9];
  float ss = 0.0f;
#pragma unroll
  for (int it = 0; it < 9; ++it) {
    int f = tid + it * 256;
    int c = f / 9, r = f - c * 9;
    int dy = r / 3, dx = r - dy * 3;
    int yy = y + dy - 1, xx = x + dx - 1;
    float val = 0.0f;
    if (yy >= 0 && yy < 48 && xx >= 0 && xx < 48)
      val = s[(c * 48 + yy) * 48 + xx];
    v[it] = val;
    ss += val * val;
  }
  __shared__ float red[256];
  red[tid] = ss;
  __syncthreads();
  for (int ofs = 128; ofs > 0; ofs >>= 1) {
    if (tid < ofs) red[tid] += red[tid + ofs];
    __syncthreads();
  }
  float norm = fmaxf(sqrtf(red[0]), 1e-12f);
  _Float16* dh = dhi + ((size_t)n * HW48 + pos) * (size_t)F9;
  _Float16* dl = dlo + ((size_t)n * HW48 + pos) * (size_t)F9;
#pragma unroll
  for (int it = 0; it < 9; ++it) {
    int f = tid + it * 256;
    float xv = v[it] / norm;
    _Float16 h = (_Float16)xv;
    dh[f] = h;
    dl[f] = (_Float16)(xv - (float)h);
  }
}

// ---------------- per-channel spatial mean ----------------
__global__ void chmean_kernel(const float* __restrict__ src, float* __restrict__ out, int C, int HW) {
  int c = blockIdx.x, n = blockIdx.y;
  const float* s = src + ((size_t)n * C + c) * HW;
  float sum = 0.0f;
  for (int i = threadIdx.x; i < HW; i += blockDim.x) sum += s[i];
  __shared__ float red[256];
  red[threadIdx.x] = sum;
  __syncthreads();
  for (int ofs = 128; ofs > 0; ofs >>= 1) {
    if (threadIdx.x < ofs) red[threadIdx.x] += red[threadIdx.x + ofs];
    __syncthreads();
  }
  if (threadIdx.x == 0) out[n * C + c] = red[0] / (float)HW;
}

// ---------------- global cosine similarity ----------------
__global__ void rglob_kernel(const float* __restrict__ mref, const float* __restrict__ mlr,
                             float* __restrict__ rg) {
  int n = blockIdx.x;
  int tid = threadIdx.x; // 256
  float a = mref[n * 256 + tid];
  float b = mlr[n * 256 + tid];
  __shared__ float raa[256], rbb[256], rab[256];
  raa[tid] = a * a; rbb[tid] = b * b; rab[tid] = a * b;
  __syncthreads();
  for (int ofs = 128; ofs > 0; ofs >>= 1) {
    if (tid < ofs) { raa[tid] += raa[tid + ofs]; rbb[tid] += rbb[tid + ofs]; rab[tid] += rab[tid + ofs]; }
    __syncthreads();
  }
  if (tid == 0) {
    float na = fmaxf(sqrtf(raa[0]), 1e-12f);
    float nb = fmaxf(sqrtf(rbb[0]), 1e-12f);
    rg[n] = rab[0] / (na * nb);
  }
}

// ---------------- dynamic-k selector (JAX partitionable threefry) ----------
__device__ inline unsigned rotl32(unsigned v, int r) { return (v << r) | (v >> (32 - r)); }

__global__ void khard_kernel(const float* __restrict__ k_logits, const float* __restrict__ temp,
                             int* __restrict__ kh) {
  if (threadIdx.x != 0 || blockIdx.x != 0) return;
  const unsigned ksa[3] = {0u, 42u, 0u ^ 42u ^ 0x1BD11BDAu};
  const int R0[4] = {13, 15, 26, 6};
  const int R1[4] = {17, 29, 16, 24};
  float T = temp[0];
  for (int lvl = 0; lvl < 3; ++lvl) {
    int best = 0;
    float bv = -1e30f;
    for (int j = 0; j < 5; ++j) {
      int idx = lvl * 5 + j;
      unsigned x0 = 0u + ksa[0];
      unsigned x1 = (unsigned)idx + ksa[1];
      for (int grp = 0; grp < 5; ++grp) {
        const int* rr = (grp & 1) ? R1 : R0;
        for (int q = 0; q < 4; ++q) { x0 += x1; x1 = rotl32(x1, rr[q]); x1 ^= x0; }
        x0 += ksa[(grp + 1) % 3];
        x1 += ksa[(grp + 2) % 3] + (unsigned)(grp + 1);
      }
      unsigned bb = x0 ^ x1;
      float f = __uint_as_float((bb >> 9) | 0x3f800000u) - 1.0f;
      float u = __fadd_rn(__fmul_rn(f, 1.0f - 1e-6f), 1e-6f);
      u = fmaxf(u, 1e-6f);
      float g = -logf(-logf(u));
      float v = (k_logits[idx] + g) / T;
      if (v > bv) { bv = v; best = j; }
    }
    kh[lvl] = best + 1;
  }
}

// ---------------- split-fp16 MFMA NT GEMM --------------------------------
#define LDH 40
__global__ __launch_bounds__(256) void gemm_mfma_kernel(
    const _Float16* __restrict__ Ah, const _Float16* __restrict__ Al,
    const _Float16* __restrict__ Bh, const _Float16* __restrict__ Bl,
    float* __restrict__ C, const float* __restrict__ rg, const float* __restrict__ gwp) {
  __shared__ __align__(16) _Float16 As_h[128 * LDH];
  __shared__ __align__(16) _Float16 As_l[128 * LDH];
  __shared__ __align__(16) _Float16 Bs_h[128 * LDH];
  __shared__ __align__(16) _Float16 Bs_l[128 * LDH];
  const int n = blockIdx.z;
  const size_t nb = (size_t)n * HW48 * F9;
  const _Float16* Ahp = Ah + nb + (size_t)(blockIdx.y * 128) * F9;
  const _Float16* Alp = Al + nb + (size_t)(blockIdx.y * 128) * F9;
  const _Float16* Bhp = Bh + nb + (size_t)(blockIdx.x * 128) * F9;
  const _Float16* Blp = Bl + nb + (size_t)(blockIdx.x * 128) * F9;
  const int tid = threadIdx.x;
  const int lane = tid & 63, wid = tid >> 6;
  const int wm = (wid >> 1) * 64, wn = (wid & 1) * 64;
  const int r16 = lane & 15, quad = lane >> 4;

  floatx4 acc[4][4];
#pragma unroll
  for (int i = 0; i < 4; ++i)
#pragma unroll
    for (int j = 0; j < 4; ++j) acc[i][j] = (floatx4){0.f, 0.f, 0.f, 0.f};

  for (int k0 = 0; k0 < F9; k0 += 32) {
#pragma unroll
    for (int u = 0; u < 2; ++u) {
      int slot = tid + 256 * u;
      int row = slot >> 2, ch = slot & 3;
      size_t goff = (size_t)row * F9 + k0 + ch * 8;
      int loff = row * LDH + ch * 8;
      *(float4*)&As_h[loff] = *(const float4*)&Ahp[goff];
      *(float4*)&As_l[loff] = *(const float4*)&Alp[goff];
      *(float4*)&Bs_h[loff] = *(const float4*)&Bhp[goff];
      *(float4*)&Bs_l[loff] = *(const float4*)&Blp[goff];
    }
    __syncthreads();
    half8_t ah[4], al[4], bh[4], bl[4];
#pragma unroll
    for (int i = 0; i < 4; ++i) {
      int ra = (wm + i * 16 + r16) * LDH + quad * 8;
      ah[i] = *(const half8_t*)&As_h[ra];
      al[i] = *(const half8_t*)&As_l[ra];
      int rb = (wn + i * 16 + r16) * LDH + quad * 8;
      bh[i] = *(const half8_t*)&Bs_h[rb];
      bl[i] = *(const half8_t*)&Bs_l[rb];
    }
#pragma unroll
    for (int i = 0; i < 4; ++i)
#pragma unroll
      for (int j = 0; j < 4; ++j) {
        acc[i][j] = __builtin_amdgcn_mfma_f32_16x16x32_f16(ah[i], bh[j], acc[i][j], 0, 0, 0);
        acc[i][j] = __builtin_amdgcn_mfma_f32_16x16x32_f16(ah[i], bl[j], acc[i][j], 0, 0, 0);
        acc[i][j] = __builtin_amdgcn_mfma_f32_16x16x32_f16(al[i], bh[j], acc[i][j], 0, 0, 0);
      }
    __syncthreads();
  }
  float gw = gwp[0];
  float base = gw * rg[n];
  float w1 = 1.0f - gw;
  float* Cp = C + (size_t)n * HW48 * HW48;
#pragma unroll
  for (int i = 0; i < 4; ++i) {
#pragma unroll
    for (int j = 0; j < 4; ++j) {
#pragma unroll
      for (int r = 0; r < 4; ++r) {
        int row = blockIdx.y * 128 + wm + i * 16 + quad * 4 + r;  // p (A side)
        int col = blockIdx.x * 128 + wn + j * 16 + r16;           // q (B side)
        Cp[(size_t)row * HW48 + col] = w1 * acc[i][j][r] + base;
      }
    }
  }
}

// ---------------- top-5 per column q (over p) — parallel over p-slices -----
// Pidx output packed: (pw << 16) | ph  (ph = p/48, pw = p%48).
__global__ __launch_bounds__(256) void topk_kernel(const float* __restrict__ R,
                                                   float* __restrict__ Wsig,
                                                   int* __restrict__ Pidx) {
  const int n = blockIdx.y;
  const int tq = threadIdx.x & 15;
  const int tp = threadIdx.x >> 4;
  const int q = blockIdx.x * 16 + tq;
  const float* Rp = R + (size_t)n * HW48 * HW48 + q;
  float v0 = -3.0e38f, v1 = v0, v2 = v0, v3 = v0, v4 = v0;
  int i0 = 0, i1 = 0, i2 = 0, i3 = 0, i4 = 0;
  const int pbeg = tp * 144, pend = pbeg + 144;
  for (int p = pbeg; p < pend; ++p) {
    float val = Rp[(size_t)p * HW48];
    if (val > v4) {
      if (val > v0)      { v4=v3;i4=i3; v3=v2;i3=i2; v2=v1;i2=i1; v1=v0;i1=i0; v0=val;i0=p; }
      else if (val > v1) { v4=v3;i4=i3; v3=v2;i3=i2; v2=v1;i2=i1; v1=val;i1=p; }
      else if (val > v2) { v4=v3;i4=i3; v3=v2;i3=i2; v2=val;i2=p; }
      else if (val > v3) { v4=v3;i4=i3; v3=val;i3=p; }
      else               { v4=val;i4=p; }
    }
  }
  __shared__ float cv[16][16][5];
  __shared__ int   ci[16][16][5];
  cv[tq][tp][0] = v0; ci[tq][tp][0] = i0;
  cv[tq][tp][1] = v1; ci[tq][tp][1] = i1;
  cv[tq][tp][2] = v2; ci[tq][tp][2] = i2;
  cv[tq][tp][3] = v3; ci[tq][tp][3] = i3;
  cv[tq][tp][4] = v4; ci[tq][tp][4] = i4;
  __syncthreads();
  if (tp == 0) {
    float w0 = -3.0e38f, w1 = w0, w2 = w0, w3 = w0, w4 = w0;
    int j0 = 0, j1 = 0, j2 = 0, j3 = 0, j4 = 0;
    for (int s = 0; s < 16; ++s) {
#pragma unroll
      for (int j = 0; j < 5; ++j) {
        float val = cv[tq][s][j];
        int   pi  = ci[tq][s][j];
        if (val > w4) {
          if (val > w0)      { w4=w3;j4=j3; w3=w2;j3=j2; w2=w1;j2=j1; w1=w0;j1=j0; w0=val;j0=pi; }
          else if (val > w1) { w4=w3;j4=j3; w3=w2;j3=j2; w2=w1;j2=j1; w1=val;j1=pi; }
          else if (val > w2) { w4=w3;j4=j3; w3=w2;j3=j2; w2=val;j2=pi; }
          else if (val > w3) { w4=w3;j4=j3; w3=val;j3=pi; }
          else               { w4=val;j4=pi; }
        }
      }
    }
    size_t o = ((size_t)n * HW48 + q) * 5;
    Wsig[o + 0] = 1.0f / (1.0f + expf(-w0)); Pidx[o + 0] = ((j0 % 48) << 16) | (j0 / 48);
    Wsig[o + 1] = 1.0f / (1.0f + expf(-w1)); Pidx[o + 1] = ((j1 % 48) << 16) | (j1 / 48);
    Wsig[o + 2] = 1.0f / (1.0f + expf(-w2)); Pidx[o + 2] = ((j2 % 48) << 16) | (j2 / 48);
    Wsig[o + 3] = 1.0f / (1.0f + expf(-w3)); Pidx[o + 3] = ((j3 % 48) << 16) | (j3 / 48);
    Wsig[o + 4] = 1.0f / (1.0f + expf(-w4)); Pidx[o + 4] = ((j4 % 48) << 16) | (j4 / 48);
  }
}

// ---------------- fused transfer + fold — channel-blocked (CV ch/thread) ---
// thread = (n, c-group, spatial); per-(t,u,m) index math done once, CV gathers.
template<int CV>
__global__ __launch_bounds__(256) void transfer_kernel(const float* __restrict__ refenc,
                                                       const float* __restrict__ Wsig,
                                                       const int* __restrict__ Pidx,
                                                       const int* __restrict__ khp,
                                                       float* __restrict__ out, int C, int s,
                                                       int pad, int lvl, float kk) {
  const int Hout = 48 * s;
  const int HH = Hout * Hout;
  int sp = blockIdx.x * 256 + threadIdx.x;
  if (sp >= HH) return;
  int X = sp % Hout, Y = sp / Hout;
  int c0 = blockIdx.y * CV;
  int n = blockIdx.z;
  int kh = khp[lvl];
  int Yp = Y + pad, Xp = X + pad;
  int Qy = Yp / s, Qx = Xp / s;
  const float* rf = refenc + ((size_t)n * C + c0) * (size_t)HH;
  const float* Wq = Wsig + (size_t)n * HW48 * 5;
  const int* Pq = Pidx + (size_t)n * HW48 * 5;
  float acc[CV];
#pragma unroll
  for (int cv = 0; cv < CV; ++cv) acc[cv] = 0.0f;
  for (int t = 0; t < 3; ++t) {
    int qh = Qy - t;
    if (qh < 0 || qh >= 48) continue;
    int i = Yp - s * qh;            // kernel row offset in [0,3s)
    for (int u = 0; u < 3; ++u) {
      int qw = Qx - u;
      if (qw < 0 || qw >= 48) continue;
      int j = Xp - s * qw;
      int q = qh * 48 + qw;
      for (int m = 0; m < kh; ++m) {
        float wgt = Wq[q * 5 + m];
        int pxy = Pq[q * 5 + m];
        int ph = pxy & 0xffff, pw = pxy >> 16;
        int yy = ph * s + i - pad;
        int xx = pw * s + j - pad;
        if (yy >= 0 && yy < Hout && xx >= 0 && xx < Hout) {
          const float* rp = rf + yy * Hout + xx;
#pragma unroll
          for (int cv = 0; cv < CV; ++cv)
            acc[cv] = fmaf(wgt, rp[(size_t)cv * HH], acc[cv]);
        }
      }
    }
  }
  float* op = out + ((size_t)n * C + c0) * (size_t)HH + sp;
#pragma unroll
  for (int cv = 0; cv < CV; ++cv)
    op[(size_t)cv * HH] = acc[cv] / kk;
}

// ---------------- SE: mlp + scale ----------------
__global__ void se_mlp_kernel(const float* __restrict__ means, const float* __restrict__ w1,
                              const float* __restrict__ b1, const float* __restrict__ w2,
                              const float* __restrict__ b2, float* __restrict__ scale,
                              int C, int R) {
  int n = blockIdx.x;
  int tid = threadIdx.x;
  __shared__ float ym[256];
  __shared__ float h1[16];
  if (tid < C) ym[tid] = means[n * C + tid];
  __syncthreads();
  if (tid < R) {
    float s = b1[tid];
    for (int c = 0; c < C; ++c) s += ym[c] * w1[tid * C + c];
    h1[tid] = fmaxf(s, 0.0f);
  }
  __syncthreads();
  if (tid < C) {
    float s = b2[tid];
    for (int r = 0; r < R; ++r) s += h1[r] * w2[tid * R + r];
    scale[n * C + tid] = 1.0f / (1.0f + expf(-s));
  }
}

__global__ void se_scale_kernel(float* __restrict__ T, const float* __restrict__ scale,
                                int C, int HW, int total) {
  int idx = blockIdx.x * blockDim.x + threadIdx.x;
  if (idx >= total) return;
  int c = (idx / HW) % C;
  int n = idx / (C * HW);
  T[idx] *= scale[n * C + c];
}

extern "C" void kernel_launch(void* const* d_in, const int* in_sizes, int n_in,
                              void* d_out, int out_size, void* d_ws, size_t ws_size,
                              hipStream_t stream) {
  const float* lrsr   = (const float*)d_in[0];
  const float* refsr  = (const float*)d_in[1];
  const float* ref1   = (const float*)d_in[2];
  const float* ref2   = (const float*)d_in[3];
  const float* ref3   = (const float*)d_in[4];
  const float* klog   = (const float*)d_in[5];
  const float* temp   = (const float*)d_in[6];
  const float* gwp    = (const float*)d_in[7];
  const float* pos_w1 = (const float*)d_in[8];
  const float* pos_b1 = (const float*)d_in[9];
  const float* pos_w2 = (const float*)d_in[10];
  const float* pos_b2 = (const float*)d_in[11];
  const float* pos_w3 = (const float*)d_in[12];
  const float* pos_b3 = (const float*)d_in[13];
  const float* se1_w1 = (const float*)d_in[14];
  const float* se1_b1 = (const float*)d_in[15];
  const float* se1_w2 = (const float*)d_in[16];
  const float* se1_b2 = (const float*)d_in[17];
  const float* se2_w1 = (const float*)d_in[18];
  const float* se2_b1 = (const float*)d_in[19];
  const float* se2_w2 = (const float*)d_in[20];
  const float* se2_b2 = (const float*)d_in[21];
  const float* se3_w1 = (const float*)d_in[22];
  const float* se3_b1 = (const float*)d_in[23];
  const float* se3_w2 = (const float*)d_in[24];
  const float* se3_b2 = (const float*)d_in[25];
  float* out = (float*)d_out;
  float* ws = (float*)d_ws;

  // workspace layout (float-indexed)
  float* refsr_enc = ws + 0;                        // 1,179,648
  float* ref3_enc  = ws + 1179648;                  // 1,179,648
  float* ref2_enc  = ws + 2359296;                  // 2,359,296
  float* ref1_enc  = ws + 4718592;                  // 4,718,592
  _Float16* Ah_hi  = (_Float16*)(ws + 9437184);     // 10,616,832 halves
  _Float16* Ah_lo  = (_Float16*)(ws + 14745600);
  _Float16* Bh_hi  = (_Float16*)(ws + 20054016);
  _Float16* Bh_lo  = (_Float16*)(ws + 25362432);
  float* Rm        = ws + 30670848;                 // 10,616,832
  float* Wsig      = ws + 41287680;                 // 23,040
  int*   Pidx      = (int*)(ws + 41310720);         // 23,040
  float* mref      = ws + 41333760;                 // 512
  float* mlr       = ws + 41334272;                 // 512
  float* rg        = ws + 41334784;                 // 2
  int*   kh        = (int*)(ws + 41334788);         // 3
  float* semean    = ws + 41334792;                 // 512
  float* sescale   = ws + 41335304;                 // 512

  // output segments: (T3, T2, T1)
  float* T3 = out;
  float* T2 = out + 1179648;
  float* T1 = out + 3538944;

  // 1) position encodings
  enc_kernel<<<4608, 256, 0, stream>>>(refsr, pos_w3, pos_b3, refsr_enc, 256, 48, 64, 1179648);
  enc_kernel<<<4608, 256, 0, stream>>>(ref3, pos_w3, pos_b3, ref3_enc, 256, 48, 64, 1179648);
  enc_kernel<<<9216, 256, 0, stream>>>(ref2, pos_w2, pos_b2, ref2_enc, 128, 96, 128, 2359296);
  enc_kernel<<<18432, 256, 0, stream>>>(ref1, pos_w1, pos_b1, ref1_enc, 64, 192, 256, 4718592);

  // 2) unfold + l2norm -> split fp16 (A: encoded ref, B: raw lrsr)
  unfold_norm_kernel<<<dim3(2304, 2), 256, 0, stream>>>(refsr_enc, Ah_hi, Ah_lo);
  unfold_norm_kernel<<<dim3(2304, 2), 256, 0, stream>>>(lrsr, Bh_hi, Bh_lo);

  // 3) global similarity + k-selector
  chmean_kernel<<<dim3(256, 2), 256, 0, stream>>>(refsr_enc, mref, 256, 2304);
  chmean_kernel<<<dim3(256, 2), 256, 0, stream>>>(lrsr, mlr, 256, 2304);
  rglob_kernel<<<2, 256, 0, stream>>>(mref, mlr, rg);
  khard_kernel<<<1, 64, 0, stream>>>(klog, temp, kh);

  // 4) correlation GEMM — split-fp16 MFMA, fused R_comb epilogue
  gemm_mfma_kernel<<<dim3(18, 18, 2), 256, 0, stream>>>(Ah_hi, Ah_lo, Bh_hi, Bh_lo, Rm, rg, gwp);

  // 5) top-5 per lr position (parallel over p-slices); Pidx packed (pw<<16)|ph
  topk_kernel<<<dim3(144, 2), 256, 0, stream>>>(Rm, Wsig, Pidx);

  // 6) transfer + fold, channel-blocked direct gather
  transfer_kernel<4><<<dim3(9, 64, 2), 256, 0, stream>>>(ref3_enc, Wsig, Pidx, kh, T3, 256, 1, 1, 0, 9.0f);
  transfer_kernel<8><<<dim3(36, 16, 2), 256, 0, stream>>>(ref2_enc, Wsig, Pidx, kh, T2, 128, 2, 2, 1, 36.0f);
  transfer_kernel<8><<<dim3(144, 8, 2), 256, 0, stream>>>(ref1_enc, Wsig, Pidx, kh, T1, 64, 4, 4, 2, 144.0f);

  // 7) SE per level (means -> tiny MLP -> in-place scale)
  chmean_kernel<<<dim3(256, 2), 256, 0, stream>>>(T3, semean, 256, 2304);
  se_mlp_kernel<<<2, 256, 0, stream>>>(semean, se3_w1, se3_b1, se3_w2, se3_b2, sescale, 256, 16);
  se_scale_kernel<<<4608, 256, 0, stream>>>(T3, sescale, 256, 2304, 1179648);

  chmean_kernel<<<dim3(128, 2), 256, 0, stream>>>(T2, semean, 128, 9216);
  se_mlp_kernel<<<2, 256, 0, stream>>>(semean, se2_w1, se2_b1, se2_w2, se2_b2, sescale, 128, 8);
  se_scale_kernel<<<9216, 256, 0, stream>>>(T2, sescale, 128, 9216, 2359296);

  chmean_kernel<<<dim3(64, 2), 256, 0, stream>>>(T1, semean, 64, 36864);
  se_mlp_kernel<<<2, 256, 0, stream>>>(semean, se1_w1, se1_b1, se1_w2, se1_b2, sescale, 64, 4);
  se_scale_kernel<<<18432, 256, 0, stream>>>(T1, sescale, 64, 36864, 4718592);
}

// Round 7
// 1028.488 us; speedup vs baseline: 1.2330x; 1.2330x over previous
//
#include <hip/hip_runtime.h>
#include <cstdint>
#include <cmath>

#define HW48 2304   // 48*48 positions
#define F9   2304   // 256*9 features

typedef _Float16 half8_t __attribute__((ext_vector_type(8)));
typedef float floatx4 __attribute__((ext_vector_type(4)));

// ---------------- pos-encode: dst = src + conv3x3(posgrid) ----------------
__global__ void enc_kernel(const float* __restrict__ src, const float* __restrict__ w,
                           const float* __restrict__ b, float* __restrict__ dst,
                           int C, int H, int ms, int total) {
  int idx = blockIdx.x * blockDim.x + threadIdx.x;
  if (idx >= total) return;
  int x = idx % H;
  int y = (idx / H) % H;
  int c = (idx / (H * H)) % C;
  float scale = (float)((double)ms / (double)H);
  float msm1 = (float)(ms - 1);
  float conv = b[c];
#pragma unroll
  for (int dy = 0; dy < 3; ++dy) {
    int yy = y + dy - 1;
    if (yy < 0 || yy >= H) continue;
    float sy = fminf(fmaxf((yy + 0.5f) * scale - 0.5f, 0.0f), msm1);
    float g0 = -1.0f + 2.0f * sy / msm1;
#pragma unroll
    for (int dx = 0; dx < 3; ++dx) {
      int xx = x + dx - 1;
      if (xx < 0 || xx >= H) continue;
      float sx = fminf(fmaxf((xx + 0.5f) * scale - 0.5f, 0.0f), msm1);
      float g1 = -1.0f + 2.0f * sx / msm1;
      conv += w[((c * 2 + 0) * 3 + dy) * 3 + dx] * g0
            + w[((c * 2 + 1) * 3 + dy) * 3 + dx] * g1;
    }
  }
  dst[idx] = src[idx] + conv;
}

// ---------------- unfold(3,1,1) + l2-norm -> split-fp16 (hi, lo) ----------
__global__ void unfold_norm_kernel(const float* __restrict__ src,
                                   _Float16* __restrict__ dhi,
                                   _Float16* __restrict__ dlo) {
  int pos = blockIdx.x;          // 0..2303
  int n = blockIdx.y;
  int y = pos / 48, x = pos - (pos / 48) * 48;
  int tid = threadIdx.x;         // 256
  const float* s = src + (size_t)n * 256 * HW48;
  float v[9];
  float ss = 0.0f;
#pragma unroll
  for (int it = 0; it < 9; ++it) {
    int f = tid + it * 256;
    int c = f / 9, r = f - c * 9;
    int dy = r / 3, dx = r - dy * 3;
    int yy = y + dy - 1, xx = x + dx - 1;
    float val = 0.0f;
    if (yy >= 0 && yy < 48 && xx >= 0 && xx < 48)
      val = s[(c * 48 + yy) * 48 + xx];
    v[it] = val;
    ss += val * val;
  }
  __shared__ float red[256];
  red[tid] = ss;
  __syncthreads();
  for (int ofs = 128; ofs > 0; ofs >>= 1) {
    if (tid < ofs) red[tid] += red[tid + ofs];
    __syncthreads();
  }
  float norm = fmaxf(sqrtf(red[0]), 1e-12f);
  _Float16* dh = dhi + ((size_t)n * HW48 + pos) * (size_t)F9;
  _Float16* dl = dlo + ((size_t)n * HW48 + pos) * (size_t)F9;
#pragma unroll
  for (int it = 0; it < 9; ++it) {
    int f = tid + it * 256;
    float xv = v[it] / norm;
    _Float16 h = (_Float16)xv;
    dh[f] = h;
    dl[f] = (_Float16)(xv - (float)h);
  }
}

// ---------------- per-channel spatial mean ----------------
__global__ void chmean_kernel(const float* __restrict__ src, float* __restrict__ out, int C, int HW) {
  int c = blockIdx.x, n = blockIdx.y;
  const float* s = src + ((size_t)n * C + c) * HW;
  float sum = 0.0f;
  for (int i = threadIdx.x; i < HW; i += blockDim.x) sum += s[i];
  __shared__ float red[256];
  red[threadIdx.x] = sum;
  __syncthreads();
  for (int ofs = 128; ofs > 0; ofs >>= 1) {
    if (threadIdx.x < ofs) red[threadIdx.x] += red[threadIdx.x + ofs];
    __syncthreads();
  }
  if (threadIdx.x == 0) out[n * C + c] = red[0] / (float)HW;
}

// ---------------- global cosine similarity ----------------
__global__ void rglob_kernel(const float* __restrict__ mref, const float* __restrict__ mlr,
                             float* __restrict__ rg) {
  int n = blockIdx.x;
  int tid = threadIdx.x; // 256
  float a = mref[n * 256 + tid];
  float b = mlr[n * 256 + tid];
  __shared__ float raa[256], rbb[256], rab[256];
  raa[tid] = a * a; rbb[tid] = b * b; rab[tid] = a * b;
  __syncthreads();
  for (int ofs = 128; ofs > 0; ofs >>= 1) {
    if (tid < ofs) { raa[tid] += raa[tid + ofs]; rbb[tid] += rbb[tid + ofs]; rab[tid] += rab[tid + ofs]; }
    __syncthreads();
  }
  if (tid == 0) {
    float na = fmaxf(sqrtf(raa[0]), 1e-12f);
    float nb = fmaxf(sqrtf(rbb[0]), 1e-12f);
    rg[n] = rab[0] / (na * nb);
  }
}

// ---------------- dynamic-k selector (JAX partitionable threefry) ----------
__device__ inline unsigned rotl32(unsigned v, int r) { return (v << r) | (v >> (32 - r)); }

__global__ void khard_kernel(const float* __restrict__ k_logits, const float* __restrict__ temp,
                             int* __restrict__ kh) {
  if (threadIdx.x != 0 || blockIdx.x != 0) return;
  const unsigned ksa[3] = {0u, 42u, 0u ^ 42u ^ 0x1BD11BDAu};
  const int R0[4] = {13, 15, 26, 6};
  const int R1[4] = {17, 29, 16, 24};
  float T = temp[0];
  for (int lvl = 0; lvl < 3; ++lvl) {
    int best = 0;
    float bv = -1e30f;
    for (int j = 0; j < 5; ++j) {
      int idx = lvl * 5 + j;
      unsigned x0 = 0u + ksa[0];
      unsigned x1 = (unsigned)idx + ksa[1];
      for (int grp = 0; grp < 5; ++grp) {
        const int* rr = (grp & 1) ? R1 : R0;
        for (int q = 0; q < 4; ++q) { x0 += x1; x1 = rotl32(x1, rr[q]); x1 ^= x0; }
        x0 += ksa[(grp + 1) % 3];
        x1 += ksa[(grp + 2) % 3] + (unsigned)(grp + 1);
      }
      unsigned bb = x0 ^ x1;
      float f = __uint_as_float((bb >> 9) | 0x3f800000u) - 1.0f;
      float u = __fadd_rn(__fmul_rn(f, 1.0f - 1e-6f), 1e-6f);
      u = fmaxf(u, 1e-6f);
      float g = -logf(-logf(u));
      float v = (k_logits[idx] + g) / T;
      if (v > bv) { bv = v; best = j; }
    }
    kh[lvl] = best + 1;
  }
}

// ---------------- split-fp16 MFMA NT GEMM --------------------------------
#define LDH 40
__global__ __launch_bounds__(256) void gemm_mfma_kernel(
    const _Float16* __restrict__ Ah, const _Float16* __restrict__ Al,
    const _Float16* __restrict__ Bh, const _Float16* __restrict__ Bl,
    float* __restrict__ C, const float* __restrict__ rg, const float* __restrict__ gwp) {
  __shared__ __align__(16) _Float16 As_h[128 * LDH];
  __shared__ __align__(16) _Float16 As_l[128 * LDH];
  __shared__ __align__(16) _Float16 Bs_h[128 * LDH];
  __shared__ __align__(16) _Float16 Bs_l[128 * LDH];
  const int n = blockIdx.z;
  const size_t nb = (size_t)n * HW48 * F9;
  const _Float16* Ahp = Ah + nb + (size_t)(blockIdx.y * 128) * F9;
  const _Float16* Alp = Al + nb + (size_t)(blockIdx.y * 128) * F9;
  const _Float16* Bhp = Bh + nb + (size_t)(blockIdx.x * 128) * F9;
  const _Float16* Blp = Bl + nb + (size_t)(blockIdx.x * 128) * F9;
  const int tid = threadIdx.x;
  const int lane = tid & 63, wid = tid >> 6;
  const int wm = (wid >> 1) * 64, wn = (wid & 1) * 64;
  const int r16 = lane & 15, quad = lane >> 4;

  floatx4 acc[4][4];
#pragma unroll
  for (int i = 0; i < 4; ++i)
#pragma unroll
    for (int j = 0; j < 4; ++j) acc[i][j] = (floatx4){0.f, 0.f, 0.f, 0.f};

  for (int k0 = 0; k0 < F9; k0 += 32) {
#pragma unroll
    for (int u = 0; u < 2; ++u) {
      int slot = tid + 256 * u;
      int row = slot >> 2, ch = slot & 3;
      size_t goff = (size_t)row * F9 + k0 + ch * 8;
      int loff = row * LDH + ch * 8;
      *(float4*)&As_h[loff] = *(const float4*)&Ahp[goff];
      *(float4*)&As_l[loff] = *(const float4*)&Alp[goff];
      *(float4*)&Bs_h[loff] = *(const float4*)&Bhp[goff];
      *(float4*)&Bs_l[loff] = *(const float4*)&Blp[goff];
    }
    __syncthreads();
    half8_t ah[4], al[4], bh[4], bl[4];
#pragma unroll
    for (int i = 0; i < 4; ++i) {
      int ra = (wm + i * 16 + r16) * LDH + quad * 8;
      ah[i] = *(const half8_t*)&As_h[ra];
      al[i] = *(const half8_t*)&As_l[ra];
      int rb = (wn + i * 16 + r16) * LDH + quad * 8;
      bh[i] = *(const half8_t*)&Bs_h[rb];
      bl[i] = *(const half8_t*)&Bs_l[rb];
    }
#pragma unroll
    for (int i = 0; i < 4; ++i)
#pragma unroll
      for (int j = 0; j < 4; ++j) {
        acc[i][j] = __builtin_amdgcn_mfma_f32_16x16x32_f16(ah[i], bh[j], acc[i][j], 0, 0, 0);
        acc[i][j] = __builtin_amdgcn_mfma_f32_16x16x32_f16(ah[i], bl[j], acc[i][j], 0, 0, 0);
        acc[i][j] = __builtin_amdgcn_mfma_f32_16x16x32_f16(al[i], bh[j], acc[i][j], 0, 0, 0);
      }
    __syncthreads();
  }
  float gw = gwp[0];
  float base = gw * rg[n];
  float w1 = 1.0f - gw;
  float* Cp = C + (size_t)n * HW48 * HW48;
#pragma unroll
  for (int i = 0; i < 4; ++i) {
#pragma unroll
    for (int j = 0; j < 4; ++j) {
#pragma unroll
      for (int r = 0; r < 4; ++r) {
        int row = blockIdx.y * 128 + wm + i * 16 + quad * 4 + r;  // p (A side)
        int col = blockIdx.x * 128 + wn + j * 16 + r16;           // q (B side)
        Cp[(size_t)row * HW48 + col] = w1 * acc[i][j][r] + base;
      }
    }
  }
}

// ---------------- top-5 per column q (over p) — parallel over p-slices -----
// Output combined WP[q][5] = {sigmoid(val), bitcast((pw<<16)|ph)}.
__global__ __launch_bounds__(256) void topk_kernel(const float* __restrict__ R,
                                                   float2* __restrict__ WP) {
  const int n = blockIdx.y;
  const int tq = threadIdx.x & 15;
  const int tp = threadIdx.x >> 4;
  const int q = blockIdx.x * 16 + tq;
  const float* Rp = R + (size_t)n * HW48 * HW48 + q;
  float v0 = -3.0e38f, v1 = v0, v2 = v0, v3 = v0, v4 = v0;
  int i0 = 0, i1 = 0, i2 = 0, i3 = 0, i4 = 0;
  const int pbeg = tp * 144, pend = pbeg + 144;
  for (int p = pbeg; p < pend; ++p) {
    float val = Rp[(size_t)p * HW48];
    if (val > v4) {
      if (val > v0)      { v4=v3;i4=i3; v3=v2;i3=i2; v2=v1;i2=i1; v1=v0;i1=i0; v0=val;i0=p; }
      else if (val > v1) { v4=v3;i4=i3; v3=v2;i3=i2; v2=v1;i2=i1; v1=val;i1=p; }
      else if (val > v2) { v4=v3;i4=i3; v3=v2;i3=i2; v2=val;i2=p; }
      else if (val > v3) { v4=v3;i4=i3; v3=val;i3=p; }
      else               { v4=val;i4=p; }
    }
  }
  __shared__ float cv[16][16][5];
  __shared__ int   ci[16][16][5];
  cv[tq][tp][0] = v0; ci[tq][tp][0] = i0;
  cv[tq][tp][1] = v1; ci[tq][tp][1] = i1;
  cv[tq][tp][2] = v2; ci[tq][tp][2] = i2;
  cv[tq][tp][3] = v3; ci[tq][tp][3] = i3;
  cv[tq][tp][4] = v4; ci[tq][tp][4] = i4;
  __syncthreads();
  if (tp == 0) {
    float w0 = -3.0e38f, w1 = w0, w2 = w0, w3 = w0, w4 = w0;
    int j0 = 0, j1 = 0, j2 = 0, j3 = 0, j4 = 0;
    for (int s = 0; s < 16; ++s) {
#pragma unroll
      for (int j = 0; j < 5; ++j) {
        float val = cv[tq][s][j];
        int   pi  = ci[tq][s][j];
        if (val > w4) {
          if (val > w0)      { w4=w3;j4=j3; w3=w2;j3=j2; w2=w1;j2=j1; w1=w0;j1=j0; w0=val;j0=pi; }
          else if (val > w1) { w4=w3;j4=j3; w3=w2;j3=j2; w2=w1;j2=j1; w1=val;j1=pi; }
          else if (val > w2) { w4=w3;j4=j3; w3=w2;j3=j2; w2=val;j2=pi; }
          else if (val > w3) { w4=w3;j4=j3; w3=val;j3=pi; }
          else               { w4=val;j4=pi; }
        }
      }
    }
    float2* o = WP + ((size_t)n * HW48 + q) * 5;
    o[0] = make_float2(1.0f / (1.0f + expf(-w0)), __int_as_float(((j0 % 48) << 16) | (j0 / 48)));
    o[1] = make_float2(1.0f / (1.0f + expf(-w1)), __int_as_float(((j1 % 48) << 16) | (j1 / 48)));
    o[2] = make_float2(1.0f / (1.0f + expf(-w2)), __int_as_float(((j2 % 48) << 16) | (j2 / 48)));
    o[3] = make_float2(1.0f / (1.0f + expf(-w3)), __int_as_float(((j3 % 48) << 16) | (j3 / 48)));
    o[4] = make_float2(1.0f / (1.0f + expf(-w4)), __int_as_float(((j4 % 48) << 16) | (j4 / 48)));
  }
}

// ---------------- fused transfer + fold (per-channel, LDS candidate cache) -
// Block = 256 consecutive spatial pixels of ONE channel (HH % 256 == 0).
// Preload the block's q-window candidate rows into LDS once; hot loop
// issues only the <=45 plane gathers to VMEM.
__global__ __launch_bounds__(256) void transfer_kernel(const float* __restrict__ refenc,
                                                       const float2* __restrict__ WP,
                                                       const int* __restrict__ khp,
                                                       float* __restrict__ out, int C, int s,
                                                       int pad, int lvl, float kk, int total) {
  __shared__ float2 wp_s[1920];  // up to 8 qh-rows x 48 x 5
  const int Hout = 48 * s;
  const int HH = Hout * Hout;
  const int idx = blockIdx.x * 256 + threadIdx.x;
  // block-uniform quantities
  const int sp0 = (blockIdx.x * 256) % HH;
  const int Y0 = sp0 / Hout, Y1 = (sp0 + 255) / Hout;
  const int qh0 = max(0, (Y0 + pad) / s - 2);
  const int qh1 = min(47, (Y1 + pad) / s);
  const int nload = (qh1 - qh0 + 1) * 240;
  const int nblk = (blockIdx.x * 256) / (C * HH);
  const float2* WPn = WP + (size_t)nblk * HW48 * 5 + (size_t)qh0 * 240;
  for (int i = threadIdx.x; i < nload; i += 256) wp_s[i] = WPn[i];
  __syncthreads();
  if (idx >= total) return;

  const int sp = idx % HH;
  const int X = sp % Hout, Y = sp / Hout;
  const int c = (idx / HH) % C;
  const int n = idx / (C * HH);
  const int kh = khp[lvl];
  const int Yp = Y + pad, Xp = X + pad;
  const int Qy = Yp / s, Qx = Xp / s;
  const float* rf = refenc + ((size_t)n * C + c) * (size_t)HH;
  float acc = 0.0f;
  for (int t = 0; t < 3; ++t) {
    int qh = Qy - t;
    if (qh < 0 || qh >= 48) continue;
    int i = Yp - s * qh;            // kernel row offset in [0,3s)
    for (int u = 0; u < 3; ++u) {
      int qw = Qx - u;
      if (qw < 0 || qw >= 48) continue;
      int j = Xp - s * qw;
      int base = ((qh - qh0) * 48 + qw) * 5;
      for (int m = 0; m < kh; ++m) {
        float2 wp = wp_s[base + m];
        float wgt = wp.x;
        int pxy = __float_as_int(wp.y);
        int ph = pxy & 0xffff, pw = pxy >> 16;
        int yy = ph * s + i - pad;
        int xx = pw * s + j - pad;
        if (yy >= 0 && yy < Hout && xx >= 0 && xx < Hout)
          acc = fmaf(wgt, rf[yy * Hout + xx], acc);
      }
    }
  }
  out[idx] = acc / kk;
}

// ---------------- SE: mlp + scale ----------------
__global__ void se_mlp_kernel(const float* __restrict__ means, const float* __restrict__ w1,
                              const float* __restrict__ b1, const float* __restrict__ w2,
                              const float* __restrict__ b2, float* __restrict__ scale,
                              int C, int R) {
  int n = blockIdx.x;
  int tid = threadIdx.x;
  __shared__ float ym[256];
  __shared__ float h1[16];
  if (tid < C) ym[tid] = means[n * C + tid];
  __syncthreads();
  if (tid < R) {
    float s = b1[tid];
    for (int c = 0; c < C; ++c) s += ym[c] * w1[tid * C + c];
    h1[tid] = fmaxf(s, 0.0f);
  }
  __syncthreads();
  if (tid < C) {
    float s = b2[tid];
    for (int r = 0; r < R; ++r) s += h1[r] * w2[tid * R + r];
    scale[n * C + tid] = 1.0f / (1.0f + expf(-s));
  }
}

__global__ void se_scale_kernel(float* __restrict__ T, const float* __restrict__ scale,
                                int C, int HW, int total) {
  int idx = blockIdx.x * blockDim.x + threadIdx.x;
  if (idx >= total) return;
  int c = (idx / HW) % C;
  int n = idx / (C * HW);
  T[idx] *= scale[n * C + c];
}

extern "C" void kernel_launch(void* const* d_in, const int* in_sizes, int n_in,
                              void* d_out, int out_size, void* d_ws, size_t ws_size,
                              hipStream_t stream) {
  const float* lrsr   = (const float*)d_in[0];
  const float* refsr  = (const float*)d_in[1];
  const float* ref1   = (const float*)d_in[2];
  const float* ref2   = (const float*)d_in[3];
  const float* ref3   = (const float*)d_in[4];
  const float* klog   = (const float*)d_in[5];
  const float* temp   = (const float*)d_in[6];
  const float* gwp    = (const float*)d_in[7];
  const float* pos_w1 = (const float*)d_in[8];
  const float* pos_b1 = (const float*)d_in[9];
  const float* pos_w2 = (const float*)d_in[10];
  const float* pos_b2 = (const float*)d_in[11];
  const float* pos_w3 = (const float*)d_in[12];
  const float* pos_b3 = (const float*)d_in[13];
  const float* se1_w1 = (const float*)d_in[14];
  const float* se1_b1 = (const float*)d_in[15];
  const float* se1_w2 = (const float*)d_in[16];
  const float* se1_b2 = (const float*)d_in[17];
  const float* se2_w1 = (const float*)d_in[18];
  const float* se2_b1 = (const float*)d_in[19];
  const float* se2_w2 = (const float*)d_in[20];
  const float* se2_b2 = (const float*)d_in[21];
  const float* se3_w1 = (const float*)d_in[22];
  const float* se3_b1 = (const float*)d_in[23];
  const float* se3_w2 = (const float*)d_in[24];
  const float* se3_b2 = (const float*)d_in[25];
  float* out = (float*)d_out;
  float* ws = (float*)d_ws;

  // workspace layout (float-indexed)
  float* refsr_enc = ws + 0;                        // 1,179,648
  float* ref3_enc  = ws + 1179648;                  // 1,179,648
  float* ref2_enc  = ws + 2359296;                  // 2,359,296
  float* ref1_enc  = ws + 4718592;                  // 4,718,592
  _Float16* Ah_hi  = (_Float16*)(ws + 9437184);     // 10,616,832 halves
  _Float16* Ah_lo  = (_Float16*)(ws + 14745600);
  _Float16* Bh_hi  = (_Float16*)(ws + 20054016);
  _Float16* Bh_lo  = (_Float16*)(ws + 25362432);
  float* Rm        = ws + 30670848;                 // 10,616,832
  float2* WP       = (float2*)(ws + 41287680);      // 23,040 float2 (46,080 floats)
  float* mref      = ws + 41333760;                 // 512
  float* mlr       = ws + 41334272;                 // 512
  float* rg        = ws + 41334784;                 // 2
  int*   kh        = (int*)(ws + 41334788);         // 3
  float* semean    = ws + 41334792;                 // 512
  float* sescale   = ws + 41335304;                 // 512

  // output segments: (T3, T2, T1)
  float* T3 = out;
  float* T2 = out + 1179648;
  float* T1 = out + 3538944;

  // 1) position encodings
  enc_kernel<<<4608, 256, 0, stream>>>(refsr, pos_w3, pos_b3, refsr_enc, 256, 48, 64, 1179648);
  enc_kernel<<<4608, 256, 0, stream>>>(ref3, pos_w3, pos_b3, ref3_enc, 256, 48, 64, 1179648);
  enc_kernel<<<9216, 256, 0, stream>>>(ref2, pos_w2, pos_b2, ref2_enc, 128, 96, 128, 2359296);
  enc_kernel<<<18432, 256, 0, stream>>>(ref1, pos_w1, pos_b1, ref1_enc, 64, 192, 256, 4718592);

  // 2) unfold + l2norm -> split fp16 (A: encoded ref, B: raw lrsr)
  unfold_norm_kernel<<<dim3(2304, 2), 256, 0, stream>>>(refsr_enc, Ah_hi, Ah_lo);
  unfold_norm_kernel<<<dim3(2304, 2), 256, 0, stream>>>(lrsr, Bh_hi, Bh_lo);

  // 3) global similarity + k-selector
  chmean_kernel<<<dim3(256, 2), 256, 0, stream>>>(refsr_enc, mref, 256, 2304);
  chmean_kernel<<<dim3(256, 2), 256, 0, stream>>>(lrsr, mlr, 256, 2304);
  rglob_kernel<<<2, 256, 0, stream>>>(mref, mlr, rg);
  khard_kernel<<<1, 64, 0, stream>>>(klog, temp, kh);

  // 4) correlation GEMM — split-fp16 MFMA, fused R_comb epilogue
  gemm_mfma_kernel<<<dim3(18, 18, 2), 256, 0, stream>>>(Ah_hi, Ah_lo, Bh_hi, Bh_lo, Rm, rg, gwp);

  // 5) top-5 per lr position -> combined {sigmoid, packed pw|ph} table
  topk_kernel<<<dim3(144, 2), 256, 0, stream>>>(Rm, WP);

  // 6) transfer + fold, per-channel gather with LDS candidate cache
  transfer_kernel<<<4608, 256, 0, stream>>>(ref3_enc, WP, kh, T3, 256, 1, 1, 0, 9.0f, 1179648);
  transfer_kernel<<<9216, 256, 0, stream>>>(ref2_enc, WP, kh, T2, 128, 2, 2, 1, 36.0f, 2359296);
  transfer_kernel<<<18432, 256, 0, stream>>>(ref1_enc, WP, kh, T1, 64, 4, 4, 2, 144.0f, 4718592);

  // 7) SE per level (means -> tiny MLP -> in-place scale)
  chmean_kernel<<<dim3(256, 2), 256, 0, stream>>>(T3, semean, 256, 2304);
  se_mlp_kernel<<<2, 256, 0, stream>>>(semean, se3_w1, se3_b1, se3_w2, se3_b2, sescale, 256, 16);
  se_scale_kernel<<<4608, 256, 0, stream>>>(T3, sescale, 256, 2304, 1179648);

  chmean_kernel<<<dim3(128, 2), 256, 0, stream>>>(T2, semean, 128, 9216);
  se_mlp_kernel<<<2, 256, 0, stream>>>(semean, se2_w1, se2_b1, se2_w2, se2_b2, sescale, 128, 8);
  se_scale_kernel<<<9216, 256, 0, stream>>>(T2, sescale, 128, 9216, 2359296);

  chmean_kernel<<<dim3(64, 2), 256, 0, stream>>>(T1, semean, 64, 36864);
  se_mlp_kernel<<<2, 256, 0, stream>>>(semean, se1_w1, se1_b1, se1_w2, se1_b2, sescale, 64, 4);
  se_scale_kernel<<<18432, 256, 0, stream>>>(T1, sescale, 64, 36864, 4718592);
}

// Round 8
// 1016.924 us; speedup vs baseline: 1.2470x; 1.0114x over previous
//
#include <hip/hip_runtime.h>
#include <cstdint>
#include <cmath>

#define HW48 2304   // 48*48 positions
#define F9   2304   // 256*9 features

typedef _Float16 half8_t __attribute__((ext_vector_type(8)));
typedef float floatx4 __attribute__((ext_vector_type(4)));

// async global->LDS, 16 B per lane, wave-uniform LDS base + lane*16
__device__ __forceinline__ void gl2lds16(const _Float16* g, _Float16* l) {
  __builtin_amdgcn_global_load_lds((const __attribute__((address_space(1))) void*)g,
                                   (__attribute__((address_space(3))) void*)l,
                                   16, 0, 0);
}

// ---------------- pos-encode: dst = src + conv3x3(posgrid) ----------------
__global__ void enc_kernel(const float* __restrict__ src, const float* __restrict__ w,
                           const float* __restrict__ b, float* __restrict__ dst,
                           int C, int H, int ms, int total) {
  int idx = blockIdx.x * blockDim.x + threadIdx.x;
  if (idx >= total) return;
  int x = idx % H;
  int y = (idx / H) % H;
  int c = (idx / (H * H)) % C;
  float scale = (float)((double)ms / (double)H);
  float msm1 = (float)(ms - 1);
  float conv = b[c];
#pragma unroll
  for (int dy = 0; dy < 3; ++dy) {
    int yy = y + dy - 1;
    if (yy < 0 || yy >= H) continue;
    float sy = fminf(fmaxf((yy + 0.5f) * scale - 0.5f, 0.0f), msm1);
    float g0 = -1.0f + 2.0f * sy / msm1;
#pragma unroll
    for (int dx = 0; dx < 3; ++dx) {
      int xx = x + dx - 1;
      if (xx < 0 || xx >= H) continue;
      float sx = fminf(fmaxf((xx + 0.5f) * scale - 0.5f, 0.0f), msm1);
      float g1 = -1.0f + 2.0f * sx / msm1;
      conv += w[((c * 2 + 0) * 3 + dy) * 3 + dx] * g0
            + w[((c * 2 + 1) * 3 + dy) * 3 + dx] * g1;
    }
  }
  dst[idx] = src[idx] + conv;
}

// ---------------- unfold(3,1,1) + l2-norm -> split-fp16 (hi, lo) ----------
__global__ void unfold_norm_kernel(const float* __restrict__ src,
                                   _Float16* __restrict__ dhi,
                                   _Float16* __restrict__ dlo) {
  int pos = blockIdx.x;          // 0..2303
  int n = blockIdx.y;
  int y = pos / 48, x = pos - (pos / 48) * 48;
  int tid = threadIdx.x;         // 256
  const float* s = src + (size_t)n * 256 * HW48;
  float v[9];
  float ss = 0.0f;
#pragma unroll
  for (int it = 0; it < 9; ++it) {
    int f = tid + it * 256;
    int c = f / 9, r = f - c * 9;
    int dy = r / 3, dx = r - dy * 3;
    int yy = y + dy - 1, xx = x + dx - 1;
    float val = 0.0f;
    if (yy >= 0 && yy < 48 && xx >= 0 && xx < 48)
      val = s[(c * 48 + yy) * 48 + xx];
    v[it] = val;
    ss += val * val;
  }
  __shared__ float red[256];
  red[tid] = ss;
  __syncthreads();
  for (int ofs = 128; ofs > 0; ofs >>= 1) {
    if (tid < ofs) red[tid] += red[tid + ofs];
    __syncthreads();
  }
  float norm = fmaxf(sqrtf(red[0]), 1e-12f);
  _Float16* dh = dhi + ((size_t)n * HW48 + pos) * (size_t)F9;
  _Float16* dl = dlo + ((size_t)n * HW48 + pos) * (size_t)F9;
#pragma unroll
  for (int it = 0; it < 9; ++it) {
    int f = tid + it * 256;
    float xv = v[it] / norm;
    _Float16 h = (_Float16)xv;
    dh[f] = h;
    dl[f] = (_Float16)(xv - (float)h);
  }
}

// ---------------- per-channel spatial mean ----------------
__global__ void chmean_kernel(const float* __restrict__ src, float* __restrict__ out, int C, int HW) {
  int c = blockIdx.x, n = blockIdx.y;
  const float* s = src + ((size_t)n * C + c) * HW;
  float sum = 0.0f;
  for (int i = threadIdx.x; i < HW; i += blockDim.x) sum += s[i];
  __shared__ float red[256];
  red[threadIdx.x] = sum;
  __syncthreads();
  for (int ofs = 128; ofs > 0; ofs >>= 1) {
    if (threadIdx.x < ofs) red[threadIdx.x] += red[threadIdx.x + ofs];
    __syncthreads();
  }
  if (threadIdx.x == 0) out[n * C + c] = red[0] / (float)HW;
}

// ---------------- global cosine similarity ----------------
__global__ void rglob_kernel(const float* __restrict__ mref, const float* __restrict__ mlr,
                             float* __restrict__ rg) {
  int n = blockIdx.x;
  int tid = threadIdx.x; // 256
  float a = mref[n * 256 + tid];
  float b = mlr[n * 256 + tid];
  __shared__ float raa[256], rbb[256], rab[256];
  raa[tid] = a * a; rbb[tid] = b * b; rab[tid] = a * b;
  __syncthreads();
  for (int ofs = 128; ofs > 0; ofs >>= 1) {
    if (tid < ofs) { raa[tid] += raa[tid + ofs]; rbb[tid] += rbb[tid + ofs]; rab[tid] += rab[tid + ofs]; }
    __syncthreads();
  }
  if (tid == 0) {
    float na = fmaxf(sqrtf(raa[0]), 1e-12f);
    float nb = fmaxf(sqrtf(rbb[0]), 1e-12f);
    rg[n] = rab[0] / (na * nb);
  }
}

// ---------------- dynamic-k selector (JAX partitionable threefry) ----------
__device__ inline unsigned rotl32(unsigned v, int r) { return (v << r) | (v >> (32 - r)); }

__global__ void khard_kernel(const float* __restrict__ k_logits, const float* __restrict__ temp,
                             int* __restrict__ kh) {
  if (threadIdx.x != 0 || blockIdx.x != 0) return;
  const unsigned ksa[3] = {0u, 42u, 0u ^ 42u ^ 0x1BD11BDAu};
  const int R0[4] = {13, 15, 26, 6};
  const int R1[4] = {17, 29, 16, 24};
  float T = temp[0];
  for (int lvl = 0; lvl < 3; ++lvl) {
    int best = 0;
    float bv = -1e30f;
    for (int j = 0; j < 5; ++j) {
      int idx = lvl * 5 + j;
      unsigned x0 = 0u + ksa[0];
      unsigned x1 = (unsigned)idx + ksa[1];
      for (int grp = 0; grp < 5; ++grp) {
        const int* rr = (grp & 1) ? R1 : R0;
        for (int q = 0; q < 4; ++q) { x0 += x1; x1 = rotl32(x1, rr[q]); x1 ^= x0; }
        x0 += ksa[(grp + 1) % 3];
        x1 += ksa[(grp + 2) % 3] + (unsigned)(grp + 1);
      }
      unsigned bb = x0 ^ x1;
      float f = __uint_as_float((bb >> 9) | 0x3f800000u) - 1.0f;
      float u = __fadd_rn(__fmul_rn(f, 1.0f - 1e-6f), 1e-6f);
      u = fmaxf(u, 1e-6f);
      float g = -logf(-logf(u));
      float v = (k_logits[idx] + g) / T;
      if (v > bv) { bv = v; best = j; }
    }
    kh[lvl] = best + 1;
  }
}

// ---------------- split-fp16 MFMA NT GEMM, global_load_lds staging ---------
// LDS tile: 128 rows x 32 halves per array, unpadded (64 B rows), chunk-
// swizzled: LDS(row, c) holds global 16B-chunk c ^ (row&3) ^ ((row>>2)&3).
// ds_read_b128 fragment loads then hit each bank-group exactly 2x (free).
__global__ __launch_bounds__(256) void gemm_mfma_kernel(
    const _Float16* __restrict__ Ah, const _Float16* __restrict__ Al,
    const _Float16* __restrict__ Bh, const _Float16* __restrict__ Bl,
    float* __restrict__ C, const float* __restrict__ rg, const float* __restrict__ gwp) {
  __shared__ __align__(16) _Float16 As_h[128 * 32];
  __shared__ __align__(16) _Float16 As_l[128 * 32];
  __shared__ __align__(16) _Float16 Bs_h[128 * 32];
  __shared__ __align__(16) _Float16 Bs_l[128 * 32];
  const int n = blockIdx.z;
  const size_t nb = (size_t)n * HW48 * F9;
  const _Float16* Ahp = Ah + nb + (size_t)(blockIdx.y * 128) * F9;
  const _Float16* Alp = Al + nb + (size_t)(blockIdx.y * 128) * F9;
  const _Float16* Bhp = Bh + nb + (size_t)(blockIdx.x * 128) * F9;
  const _Float16* Blp = Bl + nb + (size_t)(blockIdx.x * 128) * F9;
  const int tid = threadIdx.x;
  const int lane = tid & 63, wid = tid >> 6;
  const int wm = (wid >> 1) * 64, wn = (wid & 1) * 64;
  const int r16 = lane & 15, quad = lane >> 4;

  // staging map: wave wid covers rows [wid*32, wid*32+32) in two 16-row subs
  int srow[2], sgoff[2], sldsb[2];
#pragma unroll
  for (int s = 0; s < 2; ++s) {
    int row = wid * 32 + s * 16 + (lane >> 2);
    int g = (lane & 3) ^ (row & 3) ^ ((row >> 2) & 3);   // global chunk to fetch
    srow[s] = row;
    sgoff[s] = row * F9 + g * 8;       // halves (k0 added per iter)
    sldsb[s] = (wid * 32 + s * 16) * 32; // wave-uniform LDS base (halves)
  }

  floatx4 acc[4][4];
#pragma unroll
  for (int i = 0; i < 4; ++i)
#pragma unroll
    for (int j = 0; j < 4; ++j) acc[i][j] = (floatx4){0.f, 0.f, 0.f, 0.f};

  // fragment LDS addresses (swizzled), halves
  int fa[4], fb[4];
#pragma unroll
  for (int i = 0; i < 4; ++i) {
    int Ra = wm + i * 16 + r16;
    fa[i] = Ra * 32 + ((quad ^ (Ra & 3) ^ ((Ra >> 2) & 3)) * 8);
    int Rb = wn + i * 16 + r16;
    fb[i] = Rb * 32 + ((quad ^ (Rb & 3) ^ ((Rb >> 2) & 3)) * 8);
  }

  for (int k0 = 0; k0 < F9; k0 += 32) {
    __syncthreads();   // prev tile reads done before overwrite
#pragma unroll
    for (int s = 0; s < 2; ++s) {
      int go = sgoff[s] + k0;
      gl2lds16(Ahp + go, &As_h[sldsb[s]]);
      gl2lds16(Alp + go, &As_l[sldsb[s]]);
      gl2lds16(Bhp + go, &Bs_h[sldsb[s]]);
      gl2lds16(Blp + go, &Bs_l[sldsb[s]]);
    }
    __syncthreads();   // drains vmcnt(0) (global_load_lds) then barrier
    half8_t ah[4], al[4], bh[4], bl[4];
#pragma unroll
    for (int i = 0; i < 4; ++i) {
      ah[i] = *(const half8_t*)&As_h[fa[i]];
      al[i] = *(const half8_t*)&As_l[fa[i]];
      bh[i] = *(const half8_t*)&Bs_h[fb[i]];
      bl[i] = *(const half8_t*)&Bs_l[fb[i]];
    }
#pragma unroll
    for (int i = 0; i < 4; ++i)
#pragma unroll
      for (int j = 0; j < 4; ++j) {
        acc[i][j] = __builtin_amdgcn_mfma_f32_16x16x32_f16(ah[i], bh[j], acc[i][j], 0, 0, 0);
        acc[i][j] = __builtin_amdgcn_mfma_f32_16x16x32_f16(ah[i], bl[j], acc[i][j], 0, 0, 0);
        acc[i][j] = __builtin_amdgcn_mfma_f32_16x16x32_f16(al[i], bh[j], acc[i][j], 0, 0, 0);
      }
  }
  float gw = gwp[0];
  float base = gw * rg[n];
  float w1 = 1.0f - gw;
  float* Cp = C + (size_t)n * HW48 * HW48;
#pragma unroll
  for (int i = 0; i < 4; ++i) {
#pragma unroll
    for (int j = 0; j < 4; ++j) {
#pragma unroll
      for (int r = 0; r < 4; ++r) {
        int row = blockIdx.y * 128 + wm + i * 16 + quad * 4 + r;  // p (A side)
        int col = blockIdx.x * 128 + wn + j * 16 + r16;           // q (B side)
        Cp[(size_t)row * HW48 + col] = w1 * acc[i][j][r] + base;
      }
    }
  }
}

// ---------------- top-5 per column q (over p) — parallel over p-slices -----
// Output combined WP[q][5] = {sigmoid(val), bitcast((pw<<16)|ph)}.
__global__ __launch_bounds__(256) void topk_kernel(const float* __restrict__ R,
                                                   float2* __restrict__ WP) {
  const int n = blockIdx.y;
  const int tq = threadIdx.x & 15;
  const int tp = threadIdx.x >> 4;
  const int q = blockIdx.x * 16 + tq;
  const float* Rp = R + (size_t)n * HW48 * HW48 + q;
  float v0 = -3.0e38f, v1 = v0, v2 = v0, v3 = v0, v4 = v0;
  int i0 = 0, i1 = 0, i2 = 0, i3 = 0, i4 = 0;
  const int pbeg = tp * 144, pend = pbeg + 144;
  for (int p = pbeg; p < pend; ++p) {
    float val = Rp[(size_t)p * HW48];
    if (val > v4) {
      if (val > v0)      { v4=v3;i4=i3; v3=v2;i3=i2; v2=v1;i2=i1; v1=v0;i1=i0; v0=val;i0=p; }
      else if (val > v1) { v4=v3;i4=i3; v3=v2;i3=i2; v2=v1;i2=i1; v1=val;i1=p; }
      else if (val > v2) { v4=v3;i4=i3; v3=v2;i3=i2; v2=val;i2=p; }
      else if (val > v3) { v4=v3;i4=i3; v3=val;i3=p; }
      else               { v4=val;i4=p; }
    }
  }
  __shared__ float cv[16][16][5];
  __shared__ int   ci[16][16][5];
  cv[tq][tp][0] = v0; ci[tq][tp][0] = i0;
  cv[tq][tp][1] = v1; ci[tq][tp][1] = i1;
  cv[tq][tp][2] = v2; ci[tq][tp][2] = i2;
  cv[tq][tp][3] = v3; ci[tq][tp][3] = i3;
  cv[tq][tp][4] = v4; ci[tq][tp][4] = i4;
  __syncthreads();
  if (tp == 0) {
    float w0 = -3.0e38f, w1 = w0, w2 = w0, w3 = w0, w4 = w0;
    int j0 = 0, j1 = 0, j2 = 0, j3 = 0, j4 = 0;
    for (int s = 0; s < 16; ++s) {
#pragma unroll
      for (int j = 0; j < 5; ++j) {
        float val = cv[tq][s][j];
        int   pi  = ci[tq][s][j];
        if (val > w4) {
          if (val > w0)      { w4=w3;j4=j3; w3=w2;j3=j2; w2=w1;j2=j1; w1=w0;j1=j0; w0=val;j0=pi; }
          else if (val > w1) { w4=w3;j4=j3; w3=w2;j3=j2; w2=w1;j2=j1; w1=val;j1=pi; }
          else if (val > w2) { w4=w3;j4=j3; w3=w2;j3=j2; w2=val;j2=pi; }
          else if (val > w3) { w4=w3;j4=j3; w3=val;j3=pi; }
          else               { w4=val;j4=pi; }
        }
      }
    }
    float2* o = WP + ((size_t)n * HW48 + q) * 5;
    o[0] = make_float2(1.0f / (1.0f + expf(-w0)), __int_as_float(((j0 % 48) << 16) | (j0 / 48)));
    o[1] = make_float2(1.0f / (1.0f + expf(-w1)), __int_as_float(((j1 % 48) << 16) | (j1 / 48)));
    o[2] = make_float2(1.0f / (1.0f + expf(-w2)), __int_as_float(((j2 % 48) << 16) | (j2 / 48)));
    o[3] = make_float2(1.0f / (1.0f + expf(-w3)), __int_as_float(((j3 % 48) << 16) | (j3 / 48)));
    o[4] = make_float2(1.0f / (1.0f + expf(-w4)), __int_as_float(((j4 % 48) << 16) | (j4 / 48)));
  }
}

// ---------------- fused transfer + fold (per-channel, LDS candidate cache) -
__global__ __launch_bounds__(256) void transfer_kernel(const float* __restrict__ refenc,
                                                       const float2* __restrict__ WP,
                                                       const int* __restrict__ khp,
                                                       float* __restrict__ out, int C, int s,
                                                       int pad, int lvl, float kk, int total) {
  __shared__ float2 wp_s[1920];  // up to 8 qh-rows x 48 x 5
  const int Hout = 48 * s;
  const int HH = Hout * Hout;
  const int idx = blockIdx.x * 256 + threadIdx.x;
  const int sp0 = (blockIdx.x * 256) % HH;
  const int Y0 = sp0 / Hout, Y1 = (sp0 + 255) / Hout;
  const int qh0 = max(0, (Y0 + pad) / s - 2);
  const int qh1 = min(47, (Y1 + pad) / s);
  const int nload = (qh1 - qh0 + 1) * 240;
  const int nblk = (blockIdx.x * 256) / (C * HH);
  const float2* WPn = WP + (size_t)nblk * HW48 * 5 + (size_t)qh0 * 240;
  for (int i = threadIdx.x; i < nload; i += 256) wp_s[i] = WPn[i];
  __syncthreads();
  if (idx >= total) return;

  const int sp = idx % HH;
  const int X = sp % Hout, Y = sp / Hout;
  const int c = (idx / HH) % C;
  const int n = idx / (C * HH);
  const int kh = khp[lvl];
  const int Yp = Y + pad, Xp = X + pad;
  const int Qy = Yp / s, Qx = Xp / s;
  const float* rf = refenc + ((size_t)n * C + c) * (size_t)HH;
  float acc = 0.0f;
  for (int t = 0; t < 3; ++t) {
    int qh = Qy - t;
    if (qh < 0 || qh >= 48) continue;
    int i = Yp - s * qh;            // kernel row offset in [0,3s)
    for (int u = 0; u < 3; ++u) {
      int qw = Qx - u;
      if (qw < 0 || qw >= 48) continue;
      int j = Xp - s * qw;
      int base = ((qh - qh0) * 48 + qw) * 5;
      for (int m = 0; m < kh; ++m) {
        float2 wp = wp_s[base + m];
        float wgt = wp.x;
        int pxy = __float_as_int(wp.y);
        int ph = pxy & 0xffff, pw = pxy >> 16;
        int yy = ph * s + i - pad;
        int xx = pw * s + j - pad;
        if (yy >= 0 && yy < Hout && xx >= 0 && xx < Hout)
          acc = fmaf(wgt, rf[yy * Hout + xx], acc);
      }
    }
  }
  out[idx] = acc / kk;
}

// ---------------- SE: mlp + scale ----------------
__global__ void se_mlp_kernel(const float* __restrict__ means, const float* __restrict__ w1,
                              const float* __restrict__ b1, const float* __restrict__ w2,
                              const float* __restrict__ b2, float* __restrict__ scale,
                              int C, int R) {
  int n = blockIdx.x;
  int tid = threadIdx.x;
  __shared__ float ym[256];
  __shared__ float h1[16];
  if (tid < C) ym[tid] = means[n * C + tid];
  __syncthreads();
  if (tid < R) {
    float s = b1[tid];
    for (int c = 0; c < C; ++c) s += ym[c] * w1[tid * C + c];
    h1[tid] = fmaxf(s, 0.0f);
  }
  __syncthreads();
  if (tid < C) {
    float s = b2[tid];
    for (int r = 0; r < R; ++r) s += h1[r] * w2[tid * R + r];
    scale[n * C + tid] = 1.0f / (1.0f + expf(-s));
  }
}

__global__ void se_scale_kernel(float* __restrict__ T, const float* __restrict__ scale,
                                int C, int HW, int total) {
  int idx = blockIdx.x * blockDim.x + threadIdx.x;
  if (idx >= total) return;
  int c = (idx / HW) % C;
  int n = idx / (C * HW);
  T[idx] *= scale[n * C + c];
}

extern "C" void kernel_launch(void* const* d_in, const int* in_sizes, int n_in,
                              void* d_out, int out_size, void* d_ws, size_t ws_size,
                              hipStream_t stream) {
  const float* lrsr   = (const float*)d_in[0];
  const float* refsr  = (const float*)d_in[1];
  const float* ref1   = (const float*)d_in[2];
  const float* ref2   = (const float*)d_in[3];
  const float* ref3   = (const float*)d_in[4];
  const float* klog   = (const float*)d_in[5];
  const float* temp   = (const float*)d_in[6];
  const float* gwp    = (const float*)d_in[7];
  const float* pos_w1 = (const float*)d_in[8];
  const float* pos_b1 = (const float*)d_in[9];
  const float* pos_w2 = (const float*)d_in[10];
  const float* pos_b2 = (const float*)d_in[11];
  const float* pos_w3 = (const float*)d_in[12];
  const float* pos_b3 = (const float*)d_in[13];
  const float* se1_w1 = (const float*)d_in[14];
  const float* se1_b1 = (const float*)d_in[15];
  const float* se1_w2 = (const float*)d_in[16];
  const float* se1_b2 = (const float*)d_in[17];
  const float* se2_w1 = (const float*)d_in[18];
  const float* se2_b1 = (const float*)d_in[19];
  const float* se2_w2 = (const float*)d_in[20];
  const float* se2_b2 = (const float*)d_in[21];
  const float* se3_w1 = (const float*)d_in[22];
  const float* se3_b1 = (const float*)d_in[23];
  const float* se3_w2 = (const float*)d_in[24];
  const float* se3_b2 = (const float*)d_in[25];
  float* out = (float*)d_out;
  float* ws = (float*)d_ws;

  // workspace layout (float-indexed)
  float* refsr_enc = ws + 0;                        // 1,179,648
  float* ref3_enc  = ws + 1179648;                  // 1,179,648
  float* ref2_enc  = ws + 2359296;                  // 2,359,296
  float* ref1_enc  = ws + 4718592;                  // 4,718,592
  _Float16* Ah_hi  = (_Float16*)(ws + 9437184);     // 10,616,832 halves
  _Float16* Ah_lo  = (_Float16*)(ws + 14745600);
  _Float16* Bh_hi  = (_Float16*)(ws + 20054016);
  _Float16* Bh_lo  = (_Float16*)(ws + 25362432);
  float* Rm        = ws + 30670848;                 // 10,616,832
  float2* WP       = (float2*)(ws + 41287680);      // 23,040 float2 (46,080 floats)
  float* mref      = ws + 41333760;                 // 512
  float* mlr       = ws + 41334272;                 // 512
  float* rg        = ws + 41334784;                 // 2
  int*   kh        = (int*)(ws + 41334788);         // 3
  float* semean    = ws + 41334792;                 // 512
  float* sescale   = ws + 41335304;                 // 512

  // output segments: (T3, T2, T1)
  float* T3 = out;
  float* T2 = out + 1179648;
  float* T1 = out + 3538944;

  // 1) position encodings
  enc_kernel<<<4608, 256, 0, stream>>>(refsr, pos_w3, pos_b3, refsr_enc, 256, 48, 64, 1179648);
  enc_kernel<<<4608, 256, 0, stream>>>(ref3, pos_w3, pos_b3, ref3_enc, 256, 48, 64, 1179648);
  enc_kernel<<<9216, 256, 0, stream>>>(ref2, pos_w2, pos_b2, ref2_enc, 128, 96, 128, 2359296);
  enc_kernel<<<18432, 256, 0, stream>>>(ref1, pos_w1, pos_b1, ref1_enc, 64, 192, 256, 4718592);

  // 2) unfold + l2norm -> split fp16 (A: encoded ref, B: raw lrsr)
  unfold_norm_kernel<<<dim3(2304, 2), 256, 0, stream>>>(refsr_enc, Ah_hi, Ah_lo);
  unfold_norm_kernel<<<dim3(2304, 2), 256, 0, stream>>>(lrsr, Bh_hi, Bh_lo);

  // 3) global similarity + k-selector
  chmean_kernel<<<dim3(256, 2), 256, 0, stream>>>(refsr_enc, mref, 256, 2304);
  chmean_kernel<<<dim3(256, 2), 256, 0, stream>>>(lrsr, mlr, 256, 2304);
  rglob_kernel<<<2, 256, 0, stream>>>(mref, mlr, rg);
  khard_kernel<<<1, 64, 0, stream>>>(klog, temp, kh);

  // 4) correlation GEMM — split-fp16 MFMA, global_load_lds staging
  gemm_mfma_kernel<<<dim3(18, 18, 2), 256, 0, stream>>>(Ah_hi, Ah_lo, Bh_hi, Bh_lo, Rm, rg, gwp);

  // 5) top-5 per lr position -> combined {sigmoid, packed pw|ph} table
  topk_kernel<<<dim3(144, 2), 256, 0, stream>>>(Rm, WP);

  // 6) transfer + fold, per-channel gather with LDS candidate cache
  transfer_kernel<<<4608, 256, 0, stream>>>(ref3_enc, WP, kh, T3, 256, 1, 1, 0, 9.0f, 1179648);
  transfer_kernel<<<9216, 256, 0, stream>>>(ref2_enc, WP, kh, T2, 128, 2, 2, 1, 36.0f, 2359296);
  transfer_kernel<<<18432, 256, 0, stream>>>(ref1_enc, WP, kh, T1, 64, 4, 4, 2, 144.0f, 4718592);

  // 7) SE per level (means -> tiny MLP -> in-place scale)
  chmean_kernel<<<dim3(256, 2), 256, 0, stream>>>(T3, semean, 256, 2304);
  se_mlp_kernel<<<2, 256, 0, stream>>>(semean, se3_w1, se3_b1, se3_w2, se3_b2, sescale, 256, 16);
  se_scale_kernel<<<4608, 256, 0, stream>>>(T3, sescale, 256, 2304, 1179648);

  chmean_kernel<<<dim3(128, 2), 256, 0, stream>>>(T2, semean, 128, 9216);
  se_mlp_kernel<<<2, 256, 0, stream>>>(semean, se2_w1, se2_b1, se2_w2, se2_b2, sescale, 128, 8);
  se_scale_kernel<<<9216, 256, 0, stream>>>(T2, sescale, 128, 9216, 2359296);

  chmean_kernel<<<dim3(64, 2), 256, 0, stream>>>(T1, semean, 64, 36864);
  se_mlp_kernel<<<2, 256, 0, stream>>>(semean, se1_w1, se1_b1, se1_w2, se1_b2, sescale, 64, 4);
  se_scale_kernel<<<18432, 256, 0, stream>>>(T1, sescale, 64, 36864, 4718592);
}